// Round 5
// baseline (14.106 us; speedup 1.0000x reference)
//
#include <hip/hip_runtime.h>
#include <math.h>

// HQNN: x in [0,16) -> output depends only on the 4-bit value.
// R4: two-kernel split. Kernel A (1 block) computes the 16x4 LUT into d_ws
//     (pays the trig + shfl-chain preamble ONCE). Kernel B is a pure
//     streaming gather with near-zero preamble: coalesced x loads, L1-hot
//     table reads from global, coalesced nontemporal f4 stores.

typedef float f4 __attribute__((ext_vector_type(4)));

__device__ __forceinline__ float bperm(int addr, float v) {
    return __int_as_float(__builtin_amdgcn_ds_bpermute(addr, __float_as_int(v)));
}

// ---------------- Kernel A: build the 16x4 table (1 block, 256 threads) ----
__global__ __launch_bounds__(256) void table_kernel(
    const float* __restrict__ weights,   // [4,4,3]
    const float* __restrict__ fc_w,      // [4,4]
    const float* __restrict__ fc_b,      // [4]
    float* __restrict__ tab)             // [16,4] out (d_ws)
{
    __shared__ __align__(16) float rot4[16][4];    // gate g: {A,B,C,D}
    __shared__ float evs[16][4];                   // <Z_w> per value

    const int tid = threadIdx.x;

    // 16 Rot gates -> {A,B,C,D}; a=A+iB b=-C-iD c=C-iD d=A-iB
    if (tid < 16) {
        const float phi   = weights[tid * 3 + 0];
        const float theta = weights[tid * 3 + 1];
        const float omega = weights[tid * 3 + 2];
        const float ht = 0.5f * theta;
        const float ha = -0.5f * (phi + omega);
        const float hb =  0.5f * (phi - omega);
        const float st = __sinf(ht), ct = __cosf(ht);
        const float sa = __sinf(ha), ca = __cosf(ha);
        const float sb = __sinf(hb), cb = __cosf(hb);
        rot4[tid][0] = ca * ct;   // A
        rot4[tid][1] = sa * ct;   // B
        rot4[tid][2] = cb * st;   // C
        rot4[tid][3] = sb * st;   // D
    }

    // Composite CNOT-ring read address (same every layer)
    const int lane = tid & 63;
    const int amp  = tid & 15;
    const int v    = tid >> 4;
    int q = amp;
    q ^= (q & 1) << 3;          // CNOT(3,0)
    q ^= (q >> 1) & 1;          // CNOT(2,3)
    q ^= ((q >> 2) & 1) << 1;   // CNOT(1,2)
    q ^= ((q >> 3) & 1) << 2;   // CNOT(0,1)
    const int paddr = (((lane & 48) | q) << 2);

    __syncthreads();

    // Encoded state is exactly |v>
    float sr = (amp == v) ? 1.0f : 0.0f;
    float si = 0.0f;

    #pragma unroll
    for (int l = 0; l < 4; ++l) {
        sr = bperm(paddr, sr);
        si = bperm(paddr, si);
        #pragma unroll
        for (int w = 0; w < 4; ++w) {
            const int g = l * 4 + w;
            const int mask = 1 << (3 - w);
            const f4 gv = *reinterpret_cast<const f4*>(&rot4[g][0]);
            const float A = gv.x, Bc = gv.y, C = gv.z, D = gv.w;
            const float pr  = __shfl_xor(sr, mask);
            const float pii = __shfl_xor(si, mask);
            float nr, ni;
            if (amp & mask) {   // lower: c*partner + d*self
                nr = C * pr + D * pii + A * sr + Bc * si;
                ni = C * pii - D * pr + A * si - Bc * sr;
            } else {            // upper: a*self + b*partner
                nr = A * sr - Bc * si - C * pr + D * pii;
                ni = A * si + Bc * sr - C * pii - D * pr;
            }
            sr = nr; si = ni;
        }
    }

    // Walsh-Hadamard over the 16-lane group: lane j -> H[j]; ev[w]=H[1<<(3-w)]
    float h = sr * sr + si * si;
    #pragma unroll
    for (int m = 1; m < 16; m <<= 1) {
        const float t = __shfl_xor(h, m);
        h = (amp & m) ? (t - h) : (t + h);
    }
    if (amp == 1 || amp == 2 || amp == 4 || amp == 8) {
        const int p = __ffs(amp) - 1;
        evs[v][3 - p] = h;
    }
    __syncthreads();

    // Linear(4,4) + leaky_relu -> global table
    if (amp < 4) {
        float acc = fc_b[amp];
        #pragma unroll
        for (int w = 0; w < 4; ++w) acc += evs[v][w] * fc_w[amp * 4 + w];
        tab[v * 4 + amp] = (acc >= 0.0f) ? acc : 0.01f * acc;
    }
}

// ---------------- Kernel B: pure streaming gather ----
__global__ __launch_bounds__(256) void gather_kernel(
    const int* __restrict__ x,
    const float* __restrict__ tab,       // [16,4] in d_ws
    float* __restrict__ out,             // [B,4]
    int B)
{
    const int gid = blockIdx.x * 256 + threadIdx.x;
    const int stride = gridDim.x * 256;

    // Prefetch indices (coalesced, 4B/lane)
    int  vv[4];
    bool hv[4];
    #pragma unroll
    for (int k = 0; k < 4; ++k) {
        const int b = gid + k * stride;
        hv[k] = (b < B);
        vv[k] = hv[k] ? (__builtin_nontemporal_load(&x[b]) & 15) : 0;
    }

    const f4* tab4 = reinterpret_cast<const f4*>(tab);
    f4* __restrict__ out4 = reinterpret_cast<f4*>(out);

    #pragma unroll
    for (int k = 0; k < 4; ++k) {
        if (hv[k]) __builtin_nontemporal_store(tab4[vv[k]], &out4[gid + k * stride]);
    }
    for (int b = gid + 4 * stride; b < B; b += stride) {   // generic tail
        const int vvt = x[b] & 15;
        __builtin_nontemporal_store(tab4[vvt], &out4[b]);
    }
}

extern "C" void kernel_launch(void* const* d_in, const int* in_sizes, int n_in,
                              void* d_out, int out_size, void* d_ws, size_t ws_size,
                              hipStream_t stream) {
    const int*   x       = (const int*)d_in[0];
    const float* weights = (const float*)d_in[1];
    const float* fc_w    = (const float*)d_in[2];
    const float* fc_b    = (const float*)d_in[3];
    float*       out     = (float*)d_out;
    float*       tab     = (float*)d_ws;      // 64 floats
    const int B = in_sizes[0];

    table_kernel<<<1, 256, 0, stream>>>(weights, fc_w, fc_b, tab);

    int blocks = (B + 1023) / 1024;           // 4 elements per thread
    if (blocks > 1024) blocks = 1024;
    if (blocks < 1) blocks = 1;
    gather_kernel<<<blocks, 256, 0, stream>>>(x, tab, out, B);
}

// Round 6
// 11.495 us; speedup vs baseline: 1.2271x; 1.2271x over previous
//
#include <hip/hip_runtime.h>
#include <math.h>

// HQNN: x in [0,16) -> output depends only on the 4-bit value. 16x4 LUT + gather.
// R5: single kernel again (R4 two-kernel split cost +2.4us/node in graph replay).
//     256 blocks x 1024 threads = 1 block/CU: sim runs on threads 0..255 only
//     (4 waves, 16 values x 16 amps as before) -> per-CU duplicate preamble
//     DS work cut 4x vs R3. Waves 4..15 prefetch x and wait at the barrier.
//     x-mask (&15) deferred to post-barrier so sim waves don't stall on vmcnt.

typedef float f4 __attribute__((ext_vector_type(4)));

__device__ __forceinline__ float bperm(int addr, float v) {
    return __int_as_float(__builtin_amdgcn_ds_bpermute(addr, __float_as_int(v)));
}

__global__ __launch_bounds__(1024) void hqnn_kernel(
    const int* __restrict__ x,
    const float* __restrict__ weights,   // [4,4,3]
    const float* __restrict__ fc_w,      // [4,4]
    const float* __restrict__ fc_b,      // [4]
    float* __restrict__ out,             // [B,4]
    int B)
{
    __shared__ __align__(16) float rot4[16][4];    // gate g: {A,B,C,D}
    __shared__ float evs[16][4];                   // <Z_w> per value
    __shared__ __align__(16) float table[16][4];   // final LUT

    const int tid = threadIdx.x;
    const int gid = blockIdx.x * 1024 + tid;
    const int stride = gridDim.x * 1024;

    // ---- Weights load first: it's the head of the critical path ----
    float phi = 0.f, theta = 0.f, omega = 0.f;
    if (tid < 16) {
        phi   = weights[tid * 3 + 0];
        theta = weights[tid * 3 + 1];
        omega = weights[tid * 3 + 2];
    }

    // ---- Prefetch gather indices (all 16 waves; raw, mask later) ----
    int  raw[4];
    bool hv[4];
    #pragma unroll
    for (int k = 0; k < 4; ++k) {
        const int b = gid + k * stride;
        hv[k] = (b < B);
        raw[k] = hv[k] ? __builtin_nontemporal_load(&x[b]) : 0;
    }

    // ---- Sim on threads 0..255 only ----
    if (tid < 256) {
        // 16 Rot gates -> {A,B,C,D}; a=A+iB b=-C-iD c=C-iD d=A-iB
        if (tid < 16) {
            const float ht = 0.5f * theta;
            const float ha = -0.5f * (phi + omega);
            const float hb =  0.5f * (phi - omega);
            const float st = __sinf(ht), ct = __cosf(ht);
            const float sa = __sinf(ha), ca = __cosf(ha);
            const float sb = __sinf(hb), cb = __cosf(hb);
            rot4[tid][0] = ca * ct;   // A
            rot4[tid][1] = sa * ct;   // B
            rot4[tid][2] = cb * st;   // C
            rot4[tid][3] = sb * st;   // D
        }

        const int lane = tid & 63;
        const int amp  = tid & 15;
        const int v    = tid >> 4;

        // Composite CNOT-ring read address (same every layer)
        int q = amp;
        q ^= (q & 1) << 3;          // CNOT(3,0)
        q ^= (q >> 1) & 1;          // CNOT(2,3)
        q ^= ((q >> 2) & 1) << 1;   // CNOT(1,2)
        q ^= ((q >> 3) & 1) << 2;   // CNOT(0,1)
        const int paddr = (((lane & 48) | q) << 2);

        __builtin_amdgcn_s_barrier();   // rot4 ready (paired with else-branch barrier)

        // Encoded state is exactly |v>
        float sr = (amp == v) ? 1.0f : 0.0f;
        float si = 0.0f;

        #pragma unroll
        for (int l = 0; l < 4; ++l) {
            sr = bperm(paddr, sr);
            si = bperm(paddr, si);
            #pragma unroll
            for (int w = 0; w < 4; ++w) {
                const int g = l * 4 + w;
                const int mask = 1 << (3 - w);
                const f4 gv = *reinterpret_cast<const f4*>(&rot4[g][0]);
                const float A = gv.x, Bc = gv.y, C = gv.z, D = gv.w;
                const float pr  = __shfl_xor(sr, mask);
                const float pii = __shfl_xor(si, mask);
                float nr, ni;
                if (amp & mask) {   // lower: c*partner + d*self
                    nr = C * pr + D * pii + A * sr + Bc * si;
                    ni = C * pii - D * pr + A * si - Bc * sr;
                } else {            // upper: a*self + b*partner
                    nr = A * sr - Bc * si - C * pr + D * pii;
                    ni = A * si + Bc * sr - C * pii - D * pr;
                }
                sr = nr; si = ni;
            }
        }

        // Walsh-Hadamard over 16-lane group: lane j -> H[j]; ev[w]=H[1<<(3-w)]
        float h = sr * sr + si * si;
        #pragma unroll
        for (int m = 1; m < 16; m <<= 1) {
            const float t = __shfl_xor(h, m);
            h = (amp & m) ? (t - h) : (t + h);
        }
        if (amp == 1 || amp == 2 || amp == 4 || amp == 8) {
            const int p = __ffs(amp) - 1;
            evs[v][3 - p] = h;
        }
        __builtin_amdgcn_s_barrier();   // evs ready

        // Linear(4,4) + leaky_relu -> LUT
        if (amp < 4) {
            float acc = fc_b[amp];
            #pragma unroll
            for (int w = 0; w < 4; ++w) acc += evs[v][w] * fc_w[amp * 4 + w];
            table[v][amp] = (acc >= 0.0f) ? acc : 0.01f * acc;
        }
    } else {
        __builtin_amdgcn_s_barrier();   // match barrier 1
        __builtin_amdgcn_s_barrier();   // match barrier 2
    }
    __syncthreads();                    // table ready for everyone

    // ---- Streaming gather ----
    f4* __restrict__ out4 = reinterpret_cast<f4*>(out);
    const f4* tab4 = reinterpret_cast<const f4*>(&table[0][0]);
    #pragma unroll
    for (int k = 0; k < 4; ++k) {
        if (hv[k]) __builtin_nontemporal_store(tab4[raw[k] & 15], &out4[gid + k * stride]);
    }
    for (int b = gid + 4 * stride; b < B; b += stride) {   // generic tail
        const int vvt = x[b] & 15;
        __builtin_nontemporal_store(tab4[vvt], &out4[b]);
    }
}

extern "C" void kernel_launch(void* const* d_in, const int* in_sizes, int n_in,
                              void* d_out, int out_size, void* d_ws, size_t ws_size,
                              hipStream_t stream) {
    const int*   x       = (const int*)d_in[0];
    const float* weights = (const float*)d_in[1];
    const float* fc_w    = (const float*)d_in[2];
    const float* fc_b    = (const float*)d_in[3];
    float*       out     = (float*)d_out;
    const int B = in_sizes[0];
    int blocks = (B + 4095) / 4096;     // 4 elements per thread
    if (blocks > 256) blocks = 256;
    if (blocks < 1) blocks = 1;
    hqnn_kernel<<<blocks, 1024, 0, stream>>>(x, weights, fc_w, fc_b, out, B);
}